// Round 1
// baseline (5180.534 us; speedup 1.0000x reference)
//
#include <hip/hip_runtime.h>
#include <hip/hip_bf16.h>
#include <math.h>

#define BB   128
#define TT   2048
#define DD   4
#define HH   64
#define G4   256      // 4*H gate rows
#define AW   32       // attention dim A
#define WIN  10
#define TILE 64
#define RWS  (TILE + WIN)   // 74 rows per attention tile (halo included)

// ---------- fast activations ----------
__device__ __forceinline__ float sigf(float x) {
    return __fdividef(1.f, 1.f + __expf(-x));
}
__device__ __forceinline__ float tanhf_(float x) {
    float ax = fabsf(x);
    float t  = __expf(-2.f * ax);
    float r  = __fdividef(1.f - t, 1.f + t);
    return copysignf(r, x);
}

// =====================================================================
// Kernel 1: 2-layer LSTM. One workgroup per batch. Thread j owns gate
// row j; its weights live in registers. h-state broadcast via LDS.
// =====================================================================
__global__ __launch_bounds__(256, 1)
void lstm_kernel(const float* __restrict__ x,
                 const float* __restrict__ Wih0, const float* __restrict__ Whh0,
                 const float* __restrict__ bih0, const float* __restrict__ bhh0,
                 const float* __restrict__ Wih1, const float* __restrict__ Whh1,
                 const float* __restrict__ bih1, const float* __restrict__ bhh1,
                 float* __restrict__ lstm_out) {
    __shared__ __align__(16) float gs[G4];
    __shared__ __align__(16) float h0s[HH];
    __shared__ __align__(16) float h1s[HH];
    __shared__ __align__(16) float xbuf[256 * DD];

    const int j = threadIdx.x;
    const int b = blockIdx.x;

    // ---- weights into registers (one-time; L2-cached across WGs) ----
    float wx0, wx1, wx2, wx3;
    {
        float4 v = *(const float4*)(Wih0 + j * DD);
        wx0 = v.x; wx1 = v.y; wx2 = v.z; wx3 = v.w;
    }
    float wh0[HH], wi1[HH], wh1[HH];
#pragma unroll
    for (int k4 = 0; k4 < 16; ++k4) {
        float4 v = *(const float4*)(Whh0 + j * HH + 4 * k4);
        wh0[4*k4+0] = v.x; wh0[4*k4+1] = v.y; wh0[4*k4+2] = v.z; wh0[4*k4+3] = v.w;
    }
#pragma unroll
    for (int k4 = 0; k4 < 16; ++k4) {
        float4 v = *(const float4*)(Wih1 + j * HH + 4 * k4);
        wi1[4*k4+0] = v.x; wi1[4*k4+1] = v.y; wi1[4*k4+2] = v.z; wi1[4*k4+3] = v.w;
    }
#pragma unroll
    for (int k4 = 0; k4 < 16; ++k4) {
        float4 v = *(const float4*)(Whh1 + j * HH + 4 * k4);
        wh1[4*k4+0] = v.x; wh1[4*k4+1] = v.y; wh1[4*k4+2] = v.z; wh1[4*k4+3] = v.w;
    }
    const float bias0 = bih0[j] + bhh0[j];
    const float bias1 = bih1[j] + bhh1[j];

    float c0 = 0.f, c1 = 0.f;
    if (j < HH) { h0s[j] = 0.f; h1s[j] = 0.f; }

    const float* xrow = x + (size_t)b * TT * DD;
    float*       orow = lstm_out + (size_t)b * TT * HH;

    for (int tc = 0; tc < TT; tc += 256) {
        __syncthreads();
        // stage 256 timesteps of x (coalesced float4 per thread)
        *(float4*)(xbuf + j * 4) = *(const float4*)(xrow + (size_t)(tc + j) * DD);
        __syncthreads();

        for (int tt = 0; tt < 256; ++tt) {
            // ---- layer 0 gates ----
            float a0 = bias0
                     + xbuf[tt*4+0]*wx0 + xbuf[tt*4+1]*wx1
                     + xbuf[tt*4+2]*wx2 + xbuf[tt*4+3]*wx3;
#pragma unroll
            for (int k4 = 0; k4 < 16; ++k4) {
                float4 hv = *(const float4*)(h0s + 4 * k4);   // broadcast
                a0 += hv.x*wh0[4*k4+0] + hv.y*wh0[4*k4+1]
                    + hv.z*wh0[4*k4+2] + hv.w*wh0[4*k4+3];
            }
            gs[j] = a0;
            __syncthreads();

            // partial layer-1 gate with OLD h1 (overlaps layer-0 activation)
            float a1 = bias1;
#pragma unroll
            for (int k4 = 0; k4 < 16; ++k4) {
                float4 hv = *(const float4*)(h1s + 4 * k4);   // broadcast
                a1 += hv.x*wh1[4*k4+0] + hv.y*wh1[4*k4+1]
                    + hv.z*wh1[4*k4+2] + hv.w*wh1[4*k4+3];
            }
            if (j < HH) {                       // layer-0 activations
                float gi = gs[j], gf = gs[j+64], gg = gs[j+128], go = gs[j+192];
                float ii = sigf(gi), ff = sigf(gf), g2 = tanhf_(gg), oo = sigf(go);
                c0 = ff * c0 + ii * g2;
                h0s[j] = oo * tanhf_(c0);
            }
            __syncthreads();

            // finish layer-1 gate with NEW h0
#pragma unroll
            for (int k4 = 0; k4 < 16; ++k4) {
                float4 hv = *(const float4*)(h0s + 4 * k4);   // broadcast
                a1 += hv.x*wi1[4*k4+0] + hv.y*wi1[4*k4+1]
                    + hv.z*wi1[4*k4+2] + hv.w*wi1[4*k4+3];
            }
            gs[j] = a1;
            __syncthreads();

            if (j >= 64 && j < 128) {           // layer-1 activations
                int jj = j - 64;
                float gi = gs[jj], gf = gs[jj+64], gg = gs[jj+128], go = gs[jj+192];
                float ii = sigf(gi), ff = sigf(gf), g2 = tanhf_(gg), oo = sigf(go);
                c1 = ff * c1 + ii * g2;
                float h = oo * tanhf_(c1);
                h1s[jj] = h;
                orow[(size_t)(tc + tt) * HH + jj] = h;   // coalesced 256B
            }
            __syncthreads();
        }
    }
}

// =====================================================================
// Kernel 2: fused q/k/v + windowed attention + MLP head.
// One WG per (batch, 64-row tile). Dynamic LDS ~128 KB.
// =====================================================================
__global__ __launch_bounds__(256, 1)
void attn_kernel(const float* __restrict__ lstm,
                 const float* __restrict__ Wq, const float* __restrict__ bq,
                 const float* __restrict__ Wk, const float* __restrict__ bk,
                 const float* __restrict__ Wv, const float* __restrict__ bv,
                 const float* __restrict__ Wc, const float* __restrict__ bc,
                 const float* __restrict__ Wo1, const float* __restrict__ bo1,
                 const float* __restrict__ Wo2, const float* __restrict__ bo2,
                 float* __restrict__ out) {
    extern __shared__ float lds[];
    // transposed weights: per-k rows, lane-consecutive columns (bank-clean)
    float* WqT  = lds;               // [64][32]
    float* WkT  = WqT  + 64*32;      // [64][32]
    float* WvT  = WkT  + 64*32;      // [64][64]
    float* WcT  = WvT  + 64*64;      // [128][64]
    float* Wo1T = WcT  + 128*64;     // [64][32]
    float* bql  = Wo1T + 64*32;      // 32
    float* bkl  = bql  + 32;         // 32
    float* bvl  = bkl  + 32;         // 64
    float* bcl  = bvl  + 64;         // 64
    float* bo1l = bcl  + 64;         // 32
    float* wo2l = bo1l + 32;         // 32
    float* ho   = wo2l + 32;         // [74][64]
    float* kb   = ho   + RWS*64;     // [74][36]  (+4 pad, 16B-aligned rows)
    float* vb   = kb   + RWS*36;     // [74][64]
    float* qb   = vb   + RWS*64;     // [64][32]

    const int tid  = threadIdx.x;
    const int b    = blockIdx.x >> 5;      // T/TILE = 32 tiles
    const int tile = blockIdx.x & 31;
    const int t0   = tile * TILE;

    // ---- stage transposed weights + biases ----
    for (int i = tid; i < 32*64; i += 256) {
        int a = i >> 6, k = i & 63;
        WqT[k*32 + a] = Wq[i];
        WkT[k*32 + a] = Wk[i];
        Wo1T[k*32 + a] = Wo1[i];
    }
    for (int i = tid; i < 64*64; i += 256) {
        int h = i >> 6, k = i & 63;
        WvT[k*64 + h] = Wv[i];
    }
    for (int i = tid; i < 64*128; i += 256) {
        int h = i >> 7, k = i & 127;
        WcT[k*64 + h] = Wc[i];
    }
    if (tid < 32)       { bql[tid] = bq[tid]; bkl[tid] = bk[tid];
                          bo1l[tid] = bo1[tid]; wo2l[tid] = Wo2[tid]; }
    else if (tid < 96)  { bvl[tid-32] = bv[tid-32]; bcl[tid-32] = bc[tid-32]; }

    // ---- stage lstm_out rows [t0-WIN, t0+TILE) (zero-fill t<0) ----
    for (int i = tid; i < RWS * 16; i += 256) {   // float4 units
        int flat = i * 4;
        int row  = flat >> 6, col = flat & 63;
        int t    = t0 - WIN + row;
        float4 v = make_float4(0.f, 0.f, 0.f, 0.f);
        if (t >= 0) v = *(const float4*)(lstm + ((size_t)b * TT + t) * HH + col);
        *(float4*)(ho + row * 64 + col) = v;
    }
    __syncthreads();

    // ---- phase 1: q,k,v projections into LDS ----
    for (int i = tid; i < RWS * 64; i += 256) {        // v
        int r = i >> 6, h = i & 63;
        float acc = bvl[h];
#pragma unroll
        for (int k4 = 0; k4 < 16; ++k4) {
            float4 hv = *(const float4*)(ho + r*64 + 4*k4);
            acc += hv.x*WvT[(4*k4+0)*64+h] + hv.y*WvT[(4*k4+1)*64+h]
                 + hv.z*WvT[(4*k4+2)*64+h] + hv.w*WvT[(4*k4+3)*64+h];
        }
        vb[r*64 + h] = acc;
    }
    for (int i = tid; i < RWS * 32; i += 256) {        // k
        int r = i >> 5, a = i & 31;
        float acc = bkl[a];
#pragma unroll
        for (int k4 = 0; k4 < 16; ++k4) {
            float4 hv = *(const float4*)(ho + r*64 + 4*k4);
            acc += hv.x*WkT[(4*k4+0)*32+a] + hv.y*WkT[(4*k4+1)*32+a]
                 + hv.z*WkT[(4*k4+2)*32+a] + hv.w*WkT[(4*k4+3)*32+a];
        }
        kb[r*36 + a] = acc;
    }
    for (int i = tid; i < TILE * 32; i += 256) {       // q (tile rows only)
        int r = i >> 5, a = i & 31;
        float acc = bql[a];
#pragma unroll
        for (int k4 = 0; k4 < 16; ++k4) {
            float4 hv = *(const float4*)(ho + (r + WIN)*64 + 4*k4);
            acc += hv.x*WqT[(4*k4+0)*32+a] + hv.y*WqT[(4*k4+1)*32+a]
                 + hv.z*WqT[(4*k4+2)*32+a] + hv.w*WqT[(4*k4+3)*32+a];
        }
        qb[r*32 + a] = acc;
    }
    __syncthreads();

    // ---- phase 2: one wave per output row ----
    const int wv   = __builtin_amdgcn_readfirstlane((int)(threadIdx.x >> 6));
    const int lane = tid & 63;
    const float bo2v = bo2[0];

    for (int r = wv; r < TILE; r += 4) {
        const int t = t0 + r;
        const float hoval = ho[(r + WIN)*64 + lane];
        float cmb;
        if (t == 0) {
            cmb = hoval;                 // reference t==0 bypass
        } else {
            // scores on lanes 0..9
            float s = -1e30f;
            const bool valid = (lane < WIN) && (t - 1 - lane >= 0);
            if (valid) {
                float acc = 0.f;
                int kr = r + WIN - 1 - lane;
#pragma unroll
                for (int a4 = 0; a4 < 8; ++a4) {
                    float4 qv = *(const float4*)(qb + r*32 + 4*a4);
                    float4 kv = *(const float4*)(kb + kr*36 + 4*a4);
                    acc += qv.x*kv.x + qv.y*kv.y + qv.z*kv.z + qv.w*kv.w;
                }
                s = acc * 0.17677669529663687f;   // 1/sqrt(32)
            }
            float m = s;
#pragma unroll
            for (int off = 8; off >= 1; off >>= 1) m = fmaxf(m, __shfl_xor(m, off, 16));
            float e = valid ? __expf(s - m) : 0.f;
            float se = e;
#pragma unroll
            for (int off = 8; off >= 1; off >>= 1) se += __shfl_xor(se, off, 16);
            float wgt = __fdividef(e, se);

            // context: all 64 lanes, weights broadcast from lanes 0..9
            float ctx = 0.f;
#pragma unroll
            for (int l = 0; l < WIN; ++l) {
                float wl = __shfl(wgt, l, 64);
                ctx += wl * vb[(r + WIN - 1 - l)*64 + lane];
            }
            // combined = [lstm_row, ctx] @ Wc.T + bc
            float acc = bcl[lane];
#pragma unroll
            for (int k = 0; k < 64; ++k)
                acc += ho[(r + WIN)*64 + k] * WcT[k*64 + lane];   // broadcast * lane-consec
#pragma unroll
            for (int k = 0; k < 64; ++k)
                acc += __shfl(ctx, k, 64) * WcT[(64 + k)*64 + lane];
            cmb = acc;
        }
        // o1 (32 outputs; all lanes run the shfls)
        float o1 = bo1l[lane & 31];
#pragma unroll
        for (int k = 0; k < 64; ++k)
            o1 += __shfl(cmb, k, 64) * Wo1T[k*32 + (lane & 31)];
        o1 = fmaxf(o1, 0.f);
        float pv = (lane < 32) ? o1 * wo2l[lane] : 0.f;
#pragma unroll
        for (int off = 32; off >= 1; off >>= 1) pv += __shfl_xor(pv, off, 64);
        if (lane == 0) out[(size_t)b * TT + t] = 1.5f * tanhf(pv + bo2v);
    }
}

// =====================================================================
extern "C" void kernel_launch(void* const* d_in, const int* in_sizes, int n_in,
                              void* d_out, int out_size, void* d_ws, size_t ws_size,
                              hipStream_t stream) {
    const float* x    = (const float*)d_in[0];
    const float* Wih0 = (const float*)d_in[1];
    const float* Whh0 = (const float*)d_in[2];
    const float* bih0 = (const float*)d_in[3];
    const float* bhh0 = (const float*)d_in[4];
    const float* Wih1 = (const float*)d_in[5];
    const float* Whh1 = (const float*)d_in[6];
    const float* bih1 = (const float*)d_in[7];
    const float* bhh1 = (const float*)d_in[8];
    const float* Wq   = (const float*)d_in[9];
    const float* bq   = (const float*)d_in[10];
    const float* Wk   = (const float*)d_in[11];
    const float* bk   = (const float*)d_in[12];
    const float* Wv   = (const float*)d_in[13];
    const float* bv   = (const float*)d_in[14];
    const float* Wc   = (const float*)d_in[15];
    const float* bc   = (const float*)d_in[16];
    const float* Wo1  = (const float*)d_in[17];
    const float* bo1  = (const float*)d_in[18];
    const float* Wo2  = (const float*)d_in[19];
    const float* bo2  = (const float*)d_in[20];
    float* out = (float*)d_out;

    float* lstm_out = (float*)d_ws;   // B*T*H floats = 64 MB

    lstm_kernel<<<BB, 256, 0, stream>>>(x, Wih0, Whh0, bih0, bhh0,
                                        Wih1, Whh1, bih1, bhh1, lstm_out);

    const int LDS_BYTES = (2048 + 2048 + 4096 + 8192 + 2048 + 256
                           + RWS*64 + RWS*36 + RWS*64 + TILE*32) * 4;  // 131488
    hipFuncSetAttribute(reinterpret_cast<const void*>(attn_kernel),
                        hipFuncAttributeMaxDynamicSharedMemorySize, LDS_BYTES);
    attn_kernel<<<BB * (TT / TILE), 256, LDS_BYTES, stream>>>(
        lstm_out, Wq, bq, Wk, bk, Wv, bv, Wc, bc, Wo1, bo1, Wo2, bo2, out);
}

// Round 2
// 3878.342 us; speedup vs baseline: 1.3358x; 1.3358x over previous
//
#include <hip/hip_runtime.h>
#include <hip/hip_bf16.h>
#include <math.h>

#define BB   128
#define TT   2048
#define DD   4
#define HH   64
#define WIN  10
#define TILE 64
#define RWS  (TILE + WIN)   // 74 rows per attention tile (halo included)

// ---------- fast activations ----------
__device__ __forceinline__ float sigf(float x) {
    return __fdividef(1.f, 1.f + __expf(-x));
}
__device__ __forceinline__ float tanhf_(float x) {
    float ax = fabsf(x);
    float t  = __expf(-2.f * ax);
    float r  = __fdividef(1.f - t, 1.f + t);
    return copysignf(r, x);
}
__device__ __forceinline__ float dot4(float4 a, float4 b) {
    return a.x*b.x + a.y*b.y + a.z*b.z + a.w*b.w;
}

// =====================================================================
// Kernel 1: 2-layer LSTM. One WG per batch, 256 threads.
// thread = (unit u = tid>>2, k-slice p = tid&3). Each 4-lane group owns
// one hidden unit: computes all 4 gates' partial dots over its 16-wide
// k-slice, butterfly-reduces via __shfl_xor (no LDS), every lane applies
// activations redundantly. ONE barrier per step: layer1(t) and
// layer0(t+1) run back-to-back sharing the same h0 LDS loads; h0
// triple-buffered, h1 double-buffered.
// =====================================================================
__global__ __launch_bounds__(256, 1)
void lstm_kernel(const float* __restrict__ x,
                 const float* __restrict__ Wih0, const float* __restrict__ Whh0,
                 const float* __restrict__ bih0, const float* __restrict__ bhh0,
                 const float* __restrict__ Wih1, const float* __restrict__ Whh1,
                 const float* __restrict__ bih1, const float* __restrict__ bhh1,
                 float* __restrict__ lstm_out) {
    __shared__ __align__(16) float h0s[3][HH];
    __shared__ __align__(16) float h1s[2][HH];
    __shared__ __align__(16) float xall[TT * DD];   // 32 KB: whole batch-row of x

    const int tid = threadIdx.x;
    const int u   = tid >> 2;     // hidden unit 0..63
    const int p   = tid & 3;      // k-slice 0..3 (k = 16p..16p+15, x-dim d = p)
    const int b   = blockIdx.x;

    // ---- weights into registers ----
    // gate row r = 64*g + u; Whh0/Wih1/Whh1 slice offset = g*4096 + tid*16 (coalesced)
    float4 wh0[4][4], wi1[4][4], wh1[4][4];
    float  wx[4], b0[4], b1[4];
#pragma unroll
    for (int g = 0; g < 4; ++g) {
        wx[g] = Wih0[g * 256 + tid];          // (64g+u)*4 + p == 256g + tid
#pragma unroll
        for (int c = 0; c < 4; ++c) {
            wh0[g][c] = *(const float4*)(Whh0 + g*4096 + tid*16 + 4*c);
            wi1[g][c] = *(const float4*)(Wih1 + g*4096 + tid*16 + 4*c);
            wh1[g][c] = *(const float4*)(Whh1 + g*4096 + tid*16 + 4*c);
        }
        const int rrow = g * 64 + u;
        b0[g] = bih0[rrow] + bhh0[rrow];
        b1[g] = bih1[rrow] + bhh1[rrow];
    }

    // ---- stage all x for this batch (coalesced float4) ----
    const float* xrow = x + (size_t)b * TT * DD;
    for (int i = tid; i < TT; i += 256)
        *(float4*)(xall + i * 4) = *(const float4*)(xrow + i * 4);

    if (tid < HH) h1s[1][tid] = 0.f;          // h1 prev for t=0
    float c0 = 0.f, c1 = 0.f;
    __syncthreads();

    // ---- A(0): layer-0 step for t=0 (h0_prev = 0) ----
    {
        const float xa = xall[p];
        float g0[4];
#pragma unroll
        for (int g = 0; g < 4; ++g) g0[g] = wx[g] * xa;
#pragma unroll
        for (int g = 0; g < 4; ++g) {
            g0[g] += __shfl_xor(g0[g], 1);
            g0[g] += __shfl_xor(g0[g], 2);
            g0[g] += b0[g];
        }
        const float ii = sigf(g0[0]), ff = sigf(g0[1]);
        const float gg = tanhf_(g0[2]), oo = sigf(g0[3]);
        c0 = ii * gg; (void)ff;
        const float h0v = oo * tanhf_(c0);
        if (p == 0) h0s[0][u] = h0v;
    }

    float* orow = lstm_out + (size_t)b * TT * HH;
    int rd3 = 0, wr3 = 1;                      // t%3, (t+1)%3

    for (int t = 0; t < TT; ++t) {
        __syncthreads();                       // the ONE barrier per step

        float4 h0v4[4], h1v4[4];
        const float* h0c = h0s[rd3];           // h0 of step t (just written)
        const float* h1p = h1s[(t + 1) & 1];   // h1 of step t-1
#pragma unroll
        for (int c = 0; c < 4; ++c) {
            h0v4[c] = *(const float4*)(h0c + 16 * p + 4 * c);
            h1v4[c] = *(const float4*)(h1p + 16 * p + 4 * c);
        }

        // ---- B(t): layer 1 ----
        {
            float g1[4];
#pragma unroll
            for (int g = 0; g < 4; ++g) {
                float s = 0.f;
#pragma unroll
                for (int c = 0; c < 4; ++c)
                    s += dot4(wi1[g][c], h0v4[c]) + dot4(wh1[g][c], h1v4[c]);
                g1[g] = s;
            }
#pragma unroll
            for (int g = 0; g < 4; ++g) {
                g1[g] += __shfl_xor(g1[g], 1);
                g1[g] += __shfl_xor(g1[g], 2);
                g1[g] += b1[g];
            }
            const float ii = sigf(g1[0]), ff = sigf(g1[1]);
            const float gg = tanhf_(g1[2]), oo = sigf(g1[3]);
            c1 = ff * c1 + ii * gg;
            const float h1v = oo * tanhf_(c1);
            if (p == 0) h1s[t & 1][u] = h1v;
            if (p == 2) orow[(size_t)t * HH + u] = h1v;
        }

        // ---- A(t+1): layer 0 for next step (shares h0v4 loads) ----
        if (t + 1 < TT) {
            const float xa = xall[(t + 1) * 4 + p];
            float g0[4];
#pragma unroll
            for (int g = 0; g < 4; ++g) {
                float s = wx[g] * xa;
#pragma unroll
                for (int c = 0; c < 4; ++c)
                    s += dot4(wh0[g][c], h0v4[c]);
                g0[g] = s;
            }
#pragma unroll
            for (int g = 0; g < 4; ++g) {
                g0[g] += __shfl_xor(g0[g], 1);
                g0[g] += __shfl_xor(g0[g], 2);
                g0[g] += b0[g];
            }
            const float ii = sigf(g0[0]), ff = sigf(g0[1]);
            const float gg = tanhf_(g0[2]), oo = sigf(g0[3]);
            c0 = ff * c0 + ii * gg;
            const float h0v = oo * tanhf_(c0);
            if (p == 0) h0s[wr3][u] = h0v;
        }
        if (++rd3 == 3) rd3 = 0;
        if (++wr3 == 3) wr3 = 0;
    }
}

// =====================================================================
// Kernel 2: fused q/k/v + windowed attention + MLP head.
// All weights row-major in LDS with padded strides (68 / 132) so every
// per-lane read is a conflict-free float4; weights register-cached
// across row-groups; zero __shfl in the hot path.
// LDS plan (floats):
//   Wqp[32][68]=2176 @0        (aliased by o1s[64][33] later)
//   Wkp[32][68]=2176 @2176
//   Wvp[64][68]=4352 @4352
//   Wcp[64][132]=8448 @8704
//   Wo1p[32][68]=2176 @17152
//   bias[256]        @19328   (bq@0 bk@32 bv@64 bc@128 bo1@192 wo2@224)
//   ho[74][64]=4736  @19584
//   kb[74][36]=2664  @24320   (cmbs[64][64] alias over kb+qb)
//   qb[64][36]=2304  @26984
//   vb[74][64]=4736  @29288
//   swr[64][12]=768  @34024
//   ctxs[64][64]=4096 @34792   -> total 38888 floats = 155552 B
// =====================================================================
#define ATTN_LDS_FLOATS 38888

__global__ __launch_bounds__(256, 1)
void attn_kernel(const float* __restrict__ lstm,
                 const float* __restrict__ Wq, const float* __restrict__ bq,
                 const float* __restrict__ Wk, const float* __restrict__ bk,
                 const float* __restrict__ Wv, const float* __restrict__ bv,
                 const float* __restrict__ Wc, const float* __restrict__ bc,
                 const float* __restrict__ Wo1, const float* __restrict__ bo1,
                 const float* __restrict__ Wo2, const float* __restrict__ bo2,
                 float* __restrict__ out) {
    extern __shared__ __align__(16) float lds[];
    float* Wqp  = lds;            // [32][68]
    float* Wkp  = lds + 2176;     // [32][68]
    float* Wvp  = lds + 4352;     // [64][68]
    float* Wcp  = lds + 8704;     // [64][132]
    float* Wo1p = lds + 17152;    // [32][68]
    float* bias = lds + 19328;    // [256]
    float* ho   = lds + 19584;    // [74][64]
    float* kb   = lds + 24320;    // [74][36]
    float* qb   = lds + 26984;    // [64][36]
    float* vb   = lds + 29288;    // [74][64]
    float* swr  = lds + 34024;    // [64][12]
    float* ctxs = lds + 34792;    // [64][64]
    float* cmbs = lds + 24320;    // [64][64] alias (kb+qb dead)
    float* o1s  = lds;            // [64][33] alias (Wqp dead)

    const int tid  = threadIdx.x;
    const int b    = blockIdx.x >> 5;
    const int tile = blockIdx.x & 31;
    const int t0   = tile * TILE;

    // ---- stage weights (direct padded copies, conflict-free) ----
    for (int i = tid; i < 2048; i += 256) {
        const int r = i >> 6, k = i & 63;
        Wqp [r * 68 + k] = Wq [i];
        Wkp [r * 68 + k] = Wk [i];
        Wo1p[r * 68 + k] = Wo1[i];
    }
    for (int i = tid; i < 4096; i += 256) {
        const int r = i >> 6, k = i & 63;
        Wvp[r * 68 + k] = Wv[i];
    }
    for (int i = tid; i < 8192; i += 256) {
        const int r = i >> 7, k = i & 127;
        Wcp[r * 132 + k] = Wc[i];
    }
    if (tid < 32) {
        bias[tid]       = bq[tid];
        bias[32 + tid]  = bk[tid];
        bias[192 + tid] = bo1[tid];
        bias[224 + tid] = Wo2[tid];
    }
    if (tid >= 64 && tid < 128) {
        const int j = tid - 64;
        bias[64 + j]  = bv[j];
        bias[128 + j] = bc[j];
    }
    // ---- stage lstm rows [t0-10, t0+64), zero-fill t<0 ----
    for (int i = tid; i < RWS * 16; i += 256) {
        const int row = i >> 4, c = i & 15;
        const int t = t0 - WIN + row;
        float4 v = make_float4(0.f, 0.f, 0.f, 0.f);
        if (t >= 0) v = *(const float4*)(lstm + ((size_t)b * TT + t) * HH + 4 * c);
        *(float4*)(ho + row * 64 + 4 * c) = v;
    }
    __syncthreads();

    // ---- phase 1a: v projection. thread=(h, rq of 4), 19 rows each ----
    {
        const int h = tid & 63, rq = tid >> 6;
        const int r0 = rq * 19;
        int ri[19];
        float acc[19];
#pragma unroll
        for (int rr = 0; rr < 19; ++rr) { ri[rr] = min(r0 + rr, RWS - 1); acc[rr] = bias[64 + h]; }
        for (int k4 = 0; k4 < 16; ++k4) {
            const float4 w = *(const float4*)(Wvp + h * 68 + 4 * k4);
#pragma unroll
            for (int rr = 0; rr < 19; ++rr)
                acc[rr] += dot4(w, *(const float4*)(ho + ri[rr] * 64 + 4 * k4));
        }
#pragma unroll
        for (int rr = 0; rr < 19; ++rr) vb[ri[rr] * 64 + h] = acc[rr];
    }
    // ---- phase 1b: k projection. thread=(a, rq of 8), 10 rows each ----
    {
        const int a = tid & 31, rq = tid >> 5;
        const int r0 = rq * 10;
        int ri[10];
        float acc[10];
#pragma unroll
        for (int rr = 0; rr < 10; ++rr) { ri[rr] = min(r0 + rr, RWS - 1); acc[rr] = bias[32 + a]; }
        for (int k4 = 0; k4 < 16; ++k4) {
            const float4 w = *(const float4*)(Wkp + a * 68 + 4 * k4);
#pragma unroll
            for (int rr = 0; rr < 10; ++rr)
                acc[rr] += dot4(w, *(const float4*)(ho + ri[rr] * 64 + 4 * k4));
        }
#pragma unroll
        for (int rr = 0; rr < 10; ++rr) kb[ri[rr] * 36 + a] = acc[rr];
    }
    // ---- phase 1c: q projection. thread=(a, rq of 8), 8 rows each ----
    {
        const int a = tid & 31, rq = tid >> 5;
        float acc[8];
#pragma unroll
        for (int rr = 0; rr < 8; ++rr) acc[rr] = bias[a];
        for (int k4 = 0; k4 < 16; ++k4) {
            const float4 w = *(const float4*)(Wqp + a * 68 + 4 * k4);
#pragma unroll
            for (int rr = 0; rr < 8; ++rr)
                acc[rr] += dot4(w, *(const float4*)(ho + (rq * 8 + rr + WIN) * 64 + 4 * k4));
        }
#pragma unroll
        for (int rr = 0; rr < 8; ++rr) qb[(rq * 8 + rr) * 36 + a] = acc[rr];
    }
    __syncthreads();

    // ---- phase 2a: scores (thread per (r,l)) ----
    for (int i = tid; i < TILE * WIN; i += 256) {
        const int r = i / WIN, l = i - r * WIN;
        const int t = t0 + r;
        float s = -1e30f;
        if (t - 1 - l >= 0) {
            const int kr = r + WIN - 1 - l;
            float acc = 0.f;
#pragma unroll
            for (int a4 = 0; a4 < 8; ++a4)
                acc += dot4(*(const float4*)(qb + r * 36 + 4 * a4),
                            *(const float4*)(kb + kr * 36 + 4 * a4));
            s = acc * 0.17677669529663687f;   // 1/sqrt(32)
        }
        swr[r * 12 + l] = s;
    }
    __syncthreads();
    // ---- phase 2b: softmax per row (in place) ----
    if (tid < TILE) {
        const int r = tid;
        float sc[WIN], m = -1e30f;
#pragma unroll
        for (int l = 0; l < WIN; ++l) { sc[l] = swr[r * 12 + l]; m = fmaxf(m, sc[l]); }
        float sum = 0.f;
#pragma unroll
        for (int l = 0; l < WIN; ++l) { sc[l] = __expf(sc[l] - m); sum += sc[l]; }
        const float inv = __fdividef(1.f, sum);
#pragma unroll
        for (int l = 0; l < WIN; ++l) swr[r * 12 + l] = sc[l] * inv;
    }
    __syncthreads();
    // ---- phase 2c: context (thread per (r,h)) ----
    for (int i = tid; i < TILE * HH; i += 256) {
        const int r = i >> 6, h = i & 63;
        float acc = 0.f;
#pragma unroll
        for (int l = 0; l < WIN; ++l)
            acc += swr[r * 12 + l] * vb[(r + WIN - 1 - l) * 64 + h];
        ctxs[r * 64 + h] = acc;
    }
    __syncthreads();

    // ---- phase 3: combined = [ho, ctx] @ Wc.T + bc. thread=(h, rq of 4), 16 rows ----
    {
        const int h = tid & 63, rq = tid >> 6;
        float acc[16];
#pragma unroll
        for (int rr = 0; rr < 16; ++rr) acc[rr] = bias[128 + h];
        for (int k4 = 0; k4 < 16; ++k4) {          // lstm half
            const float4 w = *(const float4*)(Wcp + h * 132 + 4 * k4);
#pragma unroll
            for (int rr = 0; rr < 16; ++rr)
                acc[rr] += dot4(w, *(const float4*)(ho + (rq * 16 + rr + WIN) * 64 + 4 * k4));
        }
        for (int k4 = 0; k4 < 16; ++k4) {          // ctx half
            const float4 w = *(const float4*)(Wcp + h * 132 + 64 + 4 * k4);
#pragma unroll
            for (int rr = 0; rr < 16; ++rr)
                acc[rr] += dot4(w, *(const float4*)(ctxs + (rq * 16 + rr) * 64 + 4 * k4));
        }
        if (t0 == 0 && rq == 0) acc[0] = ho[WIN * 64 + h];   // t==0 bypass
#pragma unroll
        for (int rr = 0; rr < 16; ++rr) cmbs[(rq * 16 + rr) * 64 + h] = acc[rr];
    }
    __syncthreads();

    // ---- phase 4: o1 = relu(cmb @ Wo1.T + bo1). thread=(m, rq of 8), 8 rows ----
    {
        const int m = tid & 31, rq = tid >> 5;
        float acc[8];
#pragma unroll
        for (int rr = 0; rr < 8; ++rr) acc[rr] = bias[192 + m];
        for (int k4 = 0; k4 < 16; ++k4) {
            const float4 w = *(const float4*)(Wo1p + m * 68 + 4 * k4);
#pragma unroll
            for (int rr = 0; rr < 8; ++rr)
                acc[rr] += dot4(w, *(const float4*)(cmbs + (rq * 8 + rr) * 64 + 4 * k4));
        }
#pragma unroll
        for (int rr = 0; rr < 8; ++rr)
            o1s[(rq * 8 + rr) * 33 + m] = fmaxf(acc[rr], 0.f);
    }
    __syncthreads();

    // ---- phase 5: out = 1.5*tanh(o1 @ Wo2.T + bo2) ----
    if (tid < TILE) {
        const int r = tid;
        float s = bo2[0];
#pragma unroll
        for (int m = 0; m < 32; ++m) s += o1s[r * 33 + m] * bias[224 + m];
        out[(size_t)b * TT + t0 + r] = 1.5f * tanhf(s);
    }
}

// =====================================================================
extern "C" void kernel_launch(void* const* d_in, const int* in_sizes, int n_in,
                              void* d_out, int out_size, void* d_ws, size_t ws_size,
                              hipStream_t stream) {
    const float* x    = (const float*)d_in[0];
    const float* Wih0 = (const float*)d_in[1];
    const float* Whh0 = (const float*)d_in[2];
    const float* bih0 = (const float*)d_in[3];
    const float* bhh0 = (const float*)d_in[4];
    const float* Wih1 = (const float*)d_in[5];
    const float* Whh1 = (const float*)d_in[6];
    const float* bih1 = (const float*)d_in[7];
    const float* bhh1 = (const float*)d_in[8];
    const float* Wq   = (const float*)d_in[9];
    const float* bq   = (const float*)d_in[10];
    const float* Wk   = (const float*)d_in[11];
    const float* bk   = (const float*)d_in[12];
    const float* Wv   = (const float*)d_in[13];
    const float* bv   = (const float*)d_in[14];
    const float* Wc   = (const float*)d_in[15];
    const float* bc   = (const float*)d_in[16];
    const float* Wo1  = (const float*)d_in[17];
    const float* bo1  = (const float*)d_in[18];
    const float* Wo2  = (const float*)d_in[19];
    const float* bo2  = (const float*)d_in[20];
    float* out = (float*)d_out;

    float* lstm_out = (float*)d_ws;   // B*T*H floats = 64 MB

    lstm_kernel<<<BB, 256, 0, stream>>>(x, Wih0, Whh0, bih0, bhh0,
                                        Wih1, Whh1, bih1, bhh1, lstm_out);

    const int LDS_BYTES = ATTN_LDS_FLOATS * 4;   // 155552
    hipFuncSetAttribute(reinterpret_cast<const void*>(attn_kernel),
                        hipFuncAttributeMaxDynamicSharedMemorySize, LDS_BYTES);
    attn_kernel<<<BB * (TT / TILE), 256, LDS_BYTES, stream>>>(
        lstm_out, Wq, bq, Wk, bk, Wv, bv, Wc, bc, Wo1, bo1, Wo2, bo2, out);
}

// Round 3
// 3314.769 us; speedup vs baseline: 1.5629x; 1.1700x over previous
//
#include <hip/hip_runtime.h>
#include <hip/hip_bf16.h>
#include <math.h>

#define BB   128
#define TT   2048
#define DD   4
#define HH   64
#define WIN  10
#define TILE 64
#define RWS  (TILE + WIN)   // 74 rows per attention tile (halo included)

// ---------- fast activations ----------
__device__ __forceinline__ float sigf(float x) {
    return __fdividef(1.f, 1.f + __expf(-x));
}
__device__ __forceinline__ float tanhf_(float x) {
    float ax = fabsf(x);
    float t  = __expf(-2.f * ax);
    float r  = __fdividef(1.f - t, 1.f + t);
    return copysignf(r, x);
}
__device__ __forceinline__ float dot4(float4 a, float4 b) {
    return a.x*b.x + a.y*b.y + a.z*b.z + a.w*b.w;
}

// DPP quad-perm adds (VALU-speed cross-lane within quads)
__device__ __forceinline__ float qadd_xor1(float x) {
    int v = __builtin_amdgcn_mov_dpp(__float_as_int(x), 0xB1, 0xF, 0xF, true);
    return x + __int_as_float(v);
}
__device__ __forceinline__ float qadd_xor2(float x) {
    int v = __builtin_amdgcn_mov_dpp(__float_as_int(x), 0x4E, 0xF, 0xF, true);
    return x + __int_as_float(v);
}
__device__ __forceinline__ float red8(float x) {   // sum over 8-lane group
    x = qadd_xor1(x);
    x = qadd_xor2(x);
    x += __shfl_xor(x, 4, 64);
    return x;
}

// =====================================================================
// Kernel 1: 2-layer LSTM. One WG (512 threads = 8 waves) per batch.
// thread = (unit u = tid>>3, k-slice p = tid&7, 8-wide slices).
// Per-thread weights: 24 float4 (~96 VGPR) -> compiler keeps them live
// (R2's 4-wide split needed 204 VGPR; compiler re-loaded from global
// every step). h1 output buffered in LDS, flushed every 64 steps so the
// compiler's s_waitcnt vmcnt(0)-before-s_barrier drain is amortized.
// =====================================================================
__global__ __launch_bounds__(512, 2) __attribute__((amdgpu_waves_per_eu(2, 2)))
void lstm_kernel(const float* __restrict__ x,
                 const float* __restrict__ Wih0, const float* __restrict__ Whh0,
                 const float* __restrict__ bih0, const float* __restrict__ bhh0,
                 const float* __restrict__ Wih1, const float* __restrict__ Whh1,
                 const float* __restrict__ bih1, const float* __restrict__ bhh1,
                 float* __restrict__ lstm_out) {
    __shared__ __align__(16) float h0s[2][HH];
    __shared__ __align__(16) float h1s[2][HH];
    __shared__ __align__(16) float xall[TT * DD];    // 32 KB
    __shared__ __align__(16) float hbuf[64 * HH];    // 16 KB output chunk

    const int tid = threadIdx.x;
    const int u   = tid >> 3;     // hidden unit 0..63
    const int p   = tid & 7;      // k-slice 0..7 (k = 8p..8p+7)
    const int b   = blockIdx.x;

    // ---- weights into registers (coalesced: wave spans contiguous 2KB) ----
    float4 wh0[4][2], wi1[4][2], wh1[4][2];
    float  wx[4], b0g[4], b1g[4];
#pragma unroll
    for (int g = 0; g < 4; ++g) {
        const int row = g * 64 + u;
        wx[g] = (p < 4) ? Wih0[row * 4 + p] : 0.f;
        wh0[g][0] = *(const float4*)(Whh0 + row * 64 + 8 * p);
        wh0[g][1] = *(const float4*)(Whh0 + row * 64 + 8 * p + 4);
        wi1[g][0] = *(const float4*)(Wih1 + row * 64 + 8 * p);
        wi1[g][1] = *(const float4*)(Wih1 + row * 64 + 8 * p + 4);
        wh1[g][0] = *(const float4*)(Whh1 + row * 64 + 8 * p);
        wh1[g][1] = *(const float4*)(Whh1 + row * 64 + 8 * p + 4);
        b0g[g] = bih0[row] + bhh0[row];
        b1g[g] = bih1[row] + bhh1[row];
    }

    // ---- stage all x for this batch ----
    const float* xrow = x + (size_t)b * TT * DD;
    for (int i = tid; i < TT; i += 512)
        *(float4*)(xall + i * 4) = *(const float4*)(xrow + i * 4);
    if (tid < HH) h1s[1][tid] = 0.f;
    float c0 = 0.f, c1 = 0.f;
    __syncthreads();

    // ---- t=0 layer 0 (h0_prev = 0) ----
    {
        float g0v[4];
#pragma unroll
        for (int g = 0; g < 4; ++g)
            g0v[g] = red8(wx[g] * xall[p & 3]) + b0g[g];
        const float ii = sigf(g0v[0]), gg = tanhf_(g0v[2]), oo = sigf(g0v[3]);
        c0 = ii * gg;
        const float h0v = oo * tanhf_(c0);
        if (p == 0) h0s[0][u] = h0v;
    }

    float* orow = lstm_out + (size_t)b * TT * HH;

    for (int t = 0; t < TT; ++t) {
        __syncthreads();                        // one barrier per step
        const float* h0c = h0s[t & 1];          // h0(t)
        const float* h1p = h1s[(t + 1) & 1];    // h1(t-1)
        const float4 h0a = *(const float4*)(h0c + 8 * p);
        const float4 h0b = *(const float4*)(h0c + 8 * p + 4);
        const float4 h1a = *(const float4*)(h1p + 8 * p);
        const float4 h1b = *(const float4*)(h1p + 8 * p + 4);

        // layer-1 gate partials (tree: two independent accumulators)
        float g1v[4];
#pragma unroll
        for (int g = 0; g < 4; ++g) {
            const float sA = dot4(wi1[g][0], h0a) + dot4(wh1[g][0], h1a);
            const float sB = dot4(wi1[g][1], h0b) + dot4(wh1[g][1], h1b);
            g1v[g] = sA + sB;
        }
        // layer-0(t+1) partials (independent of layer-1 result)
        float g0v[4];
        const float xa = xall[(t + 1 < TT ? t + 1 : t) * 4 + (p & 3)];
#pragma unroll
        for (int g = 0; g < 4; ++g) {
            const float sA = wx[g] * xa + dot4(wh0[g][0], h0a);
            const float sB = dot4(wh0[g][1], h0b);
            g0v[g] = sA + sB;
        }
#pragma unroll
        for (int g = 0; g < 4; ++g) g1v[g] = red8(g1v[g]) + b1g[g];
#pragma unroll
        for (int g = 0; g < 4; ++g) g0v[g] = red8(g0v[g]) + b0g[g];

        {   // layer-1 activations (all lanes redundant; exact same value)
            const float ii = sigf(g1v[0]), ff = sigf(g1v[1]);
            const float gg = tanhf_(g1v[2]), oo = sigf(g1v[3]);
            c1 = ff * c1 + ii * gg;
            const float h1v = oo * tanhf_(c1);
            if (p == 0) h1s[t & 1][u] = h1v;
            if (p == 1) hbuf[(t & 63) * HH + u] = h1v;
        }
        if (t + 1 < TT) {   // layer-0 activations for t+1
            const float ii = sigf(g0v[0]), ff = sigf(g0v[1]);
            const float gg = tanhf_(g0v[2]), oo = sigf(g0v[3]);
            c0 = ff * c0 + ii * gg;
            const float h0v = oo * tanhf_(c0);
            if (p == 0) h0s[(t + 1) & 1][u] = h0v;
        }
        if ((t & 63) == 63) {                   // chunk flush (1 vmcnt drain / 64 steps)
            __syncthreads();
            float4*       dst = (float4*)(orow + (size_t)(t - 63) * HH);
            const float4* src = (const float4*)hbuf;
            dst[tid]       = src[tid];
            dst[512 + tid] = src[512 + tid];
        }
    }
}

// =====================================================================
// Kernel 2: fused q/k/v + windowed attention + MLP head.
// Weights read directly from global (L1/L2 broadcast across WGs) so LDS
// holds only data tiles (78 KB) -> 2 WGs/CU.
// LDS (floats): bias[256]@0  ho[74*64]@256  kb[74*36]@4992  qb[64*36]@7656
//   vb[74*64]@9960  swr[64*12]@14696  ctxs[64*64]@15464  total 19560
//   aliases: cmbs[64*64]@4992 (kb+qb dead)   o1s[64*33]@9960 (vb dead)
// =====================================================================
#define ATTN_LDS_FLOATS 19560

__global__ __launch_bounds__(256, 2)
void attn_kernel(const float* __restrict__ lstm,
                 const float* __restrict__ Wq, const float* __restrict__ bq,
                 const float* __restrict__ Wk, const float* __restrict__ bk,
                 const float* __restrict__ Wv, const float* __restrict__ bv,
                 const float* __restrict__ Wc, const float* __restrict__ bc,
                 const float* __restrict__ Wo1, const float* __restrict__ bo1,
                 const float* __restrict__ Wo2, const float* __restrict__ bo2,
                 float* __restrict__ out) {
    extern __shared__ __align__(16) float lds[];
    float* bias = lds;            // [256]
    float* ho   = lds + 256;      // [74][64]
    float* kb   = lds + 4992;     // [74][36]
    float* qb   = lds + 7656;     // [64][36]
    float* vb   = lds + 9960;     // [74][64]
    float* swr  = lds + 14696;    // [64][12]
    float* ctxs = lds + 15464;    // [64][64]
    float* cmbs = lds + 4992;     // [64][64] alias (kb+qb dead after scores)
    float* o1s  = lds + 9960;     // [64][33] alias (vb dead after context)

    const int tid  = threadIdx.x;
    const int b    = blockIdx.x >> 5;
    const int tile = blockIdx.x & 31;
    const int t0   = tile * TILE;

    if (tid < 32) {
        bias[tid]       = bq[tid];
        bias[32 + tid]  = bk[tid];
        bias[192 + tid] = bo1[tid];
        bias[224 + tid] = Wo2[tid];
    }
    if (tid >= 64 && tid < 128) {
        const int j = tid - 64;
        bias[64 + j]  = bv[j];
        bias[128 + j] = bc[j];
    }
    // ---- stage lstm rows [t0-10, t0+64), zero-fill t<0 ----
    for (int i = tid; i < RWS * 16; i += 256) {
        const int row = i >> 4, c = i & 15;
        const int t = t0 - WIN + row;
        float4 v = make_float4(0.f, 0.f, 0.f, 0.f);
        if (t >= 0) v = *(const float4*)(lstm + ((size_t)b * TT + t) * HH + 4 * c);
        *(float4*)(ho + row * 64 + 4 * c) = v;
    }
    __syncthreads();

    // ---- phase 1a: v projection. thread=(h, rq of 4), 19 rows each ----
    {
        const int h = tid & 63, rq = tid >> 6;
        const int r0 = rq * 19;
        int ri[19];
        float acc[19];
#pragma unroll
        for (int rr = 0; rr < 19; ++rr) { ri[rr] = min(r0 + rr, RWS - 1); acc[rr] = bias[64 + h]; }
#pragma unroll
        for (int k4 = 0; k4 < 16; ++k4) {
            const float4 w = *(const float4*)(Wv + h * 64 + 4 * k4);   // L1/L2
#pragma unroll
            for (int rr = 0; rr < 19; ++rr)
                acc[rr] += dot4(w, *(const float4*)(ho + ri[rr] * 64 + 4 * k4));
        }
#pragma unroll
        for (int rr = 0; rr < 19; ++rr) vb[ri[rr] * 64 + h] = acc[rr];
    }
    // ---- phase 1b: k projection. thread=(a, rq of 8), 10 rows each ----
    {
        const int a = tid & 31, rq = tid >> 5;
        const int r0 = rq * 10;
        int ri[10];
        float acc[10];
#pragma unroll
        for (int rr = 0; rr < 10; ++rr) { ri[rr] = min(r0 + rr, RWS - 1); acc[rr] = bias[32 + a]; }
#pragma unroll
        for (int k4 = 0; k4 < 16; ++k4) {
            const float4 w = *(const float4*)(Wk + a * 64 + 4 * k4);
#pragma unroll
            for (int rr = 0; rr < 10; ++rr)
                acc[rr] += dot4(w, *(const float4*)(ho + ri[rr] * 64 + 4 * k4));
        }
#pragma unroll
        for (int rr = 0; rr < 10; ++rr) kb[ri[rr] * 36 + a] = acc[rr];
    }
    // ---- phase 1c: q projection. thread=(a, rq of 8), 8 rows each ----
    {
        const int a = tid & 31, rq = tid >> 5;
        float acc[8];
#pragma unroll
        for (int rr = 0; rr < 8; ++rr) acc[rr] = bias[a];
#pragma unroll
        for (int k4 = 0; k4 < 16; ++k4) {
            const float4 w = *(const float4*)(Wq + a * 64 + 4 * k4);
#pragma unroll
            for (int rr = 0; rr < 8; ++rr)
                acc[rr] += dot4(w, *(const float4*)(ho + (rq * 8 + rr + WIN) * 64 + 4 * k4));
        }
#pragma unroll
        for (int rr = 0; rr < 8; ++rr) qb[(rq * 8 + rr) * 36 + a] = acc[rr];
    }
    __syncthreads();

    // ---- phase 2a: scores (thread per (r,l)) ----
    for (int i = tid; i < TILE * WIN; i += 256) {
        const int r = i / WIN, l = i - r * WIN;
        const int t = t0 + r;
        float s = -1e30f;
        if (t - 1 - l >= 0) {
            const int kr = r + WIN - 1 - l;
            float acc = 0.f;
#pragma unroll
            for (int a4 = 0; a4 < 8; ++a4)
                acc += dot4(*(const float4*)(qb + r * 36 + 4 * a4),
                            *(const float4*)(kb + kr * 36 + 4 * a4));
            s = acc * 0.17677669529663687f;   // 1/sqrt(32)
        }
        swr[r * 12 + l] = s;
    }
    __syncthreads();
    // ---- phase 2b: softmax per row (in place) ----
    if (tid < TILE) {
        const int r = tid;
        float sc[WIN], m = -1e30f;
#pragma unroll
        for (int l = 0; l < WIN; ++l) { sc[l] = swr[r * 12 + l]; m = fmaxf(m, sc[l]); }
        float sum = 0.f;
#pragma unroll
        for (int l = 0; l < WIN; ++l) { sc[l] = __expf(sc[l] - m); sum += sc[l]; }
        const float inv = __fdividef(1.f, sum);
#pragma unroll
        for (int l = 0; l < WIN; ++l) swr[r * 12 + l] = sc[l] * inv;
    }
    __syncthreads();
    // ---- phase 2c: context (thread per (r,h)) ----
    for (int i = tid; i < TILE * HH; i += 256) {
        const int r = i >> 6, h = i & 63;
        float acc = 0.f;
#pragma unroll
        for (int l = 0; l < WIN; ++l)
            acc += swr[r * 12 + l] * vb[(r + WIN - 1 - l) * 64 + h];
        ctxs[r * 64 + h] = acc;
    }
    __syncthreads();

    // ---- phase 3: combined = [ho, ctx] @ Wc.T + bc. thread=(h, rq of 4) ----
    {
        const int h = tid & 63, rq = tid >> 6;
        float acc[16];
#pragma unroll
        for (int rr = 0; rr < 16; ++rr) acc[rr] = bias[128 + h];
#pragma unroll
        for (int k4 = 0; k4 < 16; ++k4) {          // lstm half
            const float4 w = *(const float4*)(Wc + h * 128 + 4 * k4);
#pragma unroll
            for (int rr = 0; rr < 16; ++rr)
                acc[rr] += dot4(w, *(const float4*)(ho + (rq * 16 + rr + WIN) * 64 + 4 * k4));
        }
#pragma unroll
        for (int k4 = 0; k4 < 16; ++k4) {          // ctx half
            const float4 w = *(const float4*)(Wc + h * 128 + 64 + 4 * k4);
#pragma unroll
            for (int rr = 0; rr < 16; ++rr)
                acc[rr] += dot4(w, *(const float4*)(ctxs + (rq * 16 + rr) * 64 + 4 * k4));
        }
        if (t0 == 0 && rq == 0) acc[0] = ho[WIN * 64 + h];   // t==0 bypass
#pragma unroll
        for (int rr = 0; rr < 16; ++rr) cmbs[(rq * 16 + rr) * 64 + h] = acc[rr];
    }
    __syncthreads();

    // ---- phase 4: o1 = relu(cmb @ Wo1.T + bo1). thread=(m, rq of 8) ----
    {
        const int m = tid & 31, rq = tid >> 5;
        float acc[8];
#pragma unroll
        for (int rr = 0; rr < 8; ++rr) acc[rr] = bias[192 + m];
#pragma unroll
        for (int k4 = 0; k4 < 16; ++k4) {
            const float4 w = *(const float4*)(Wo1 + m * 64 + 4 * k4);
#pragma unroll
            for (int rr = 0; rr < 8; ++rr)
                acc[rr] += dot4(w, *(const float4*)(cmbs + (rq * 8 + rr) * 64 + 4 * k4));
        }
#pragma unroll
        for (int rr = 0; rr < 8; ++rr)
            o1s[(rq * 8 + rr) * 33 + m] = fmaxf(acc[rr], 0.f);
    }
    __syncthreads();

    // ---- phase 5: out = 1.5*tanh(o1 @ Wo2.T + bo2) ----
    if (tid < TILE) {
        const int r = tid;
        float s = bo2[0];
#pragma unroll
        for (int m = 0; m < 32; ++m) s += o1s[r * 33 + m] * bias[224 + m];
        out[(size_t)b * TT + t0 + r] = 1.5f * tanhf(s);
    }
}

// =====================================================================
extern "C" void kernel_launch(void* const* d_in, const int* in_sizes, int n_in,
                              void* d_out, int out_size, void* d_ws, size_t ws_size,
                              hipStream_t stream) {
    const float* x    = (const float*)d_in[0];
    const float* Wih0 = (const float*)d_in[1];
    const float* Whh0 = (const float*)d_in[2];
    const float* bih0 = (const float*)d_in[3];
    const float* bhh0 = (const float*)d_in[4];
    const float* Wih1 = (const float*)d_in[5];
    const float* Whh1 = (const float*)d_in[6];
    const float* bih1 = (const float*)d_in[7];
    const float* bhh1 = (const float*)d_in[8];
    const float* Wq   = (const float*)d_in[9];
    const float* bq   = (const float*)d_in[10];
    const float* Wk   = (const float*)d_in[11];
    const float* bk   = (const float*)d_in[12];
    const float* Wv   = (const float*)d_in[13];
    const float* bv   = (const float*)d_in[14];
    const float* Wc   = (const float*)d_in[15];
    const float* bc   = (const float*)d_in[16];
    const float* Wo1  = (const float*)d_in[17];
    const float* bo1  = (const float*)d_in[18];
    const float* Wo2  = (const float*)d_in[19];
    const float* bo2  = (const float*)d_in[20];
    float* out = (float*)d_out;

    float* lstm_out = (float*)d_ws;   // B*T*H floats = 64 MB

    lstm_kernel<<<BB, 512, 0, stream>>>(x, Wih0, Whh0, bih0, bhh0,
                                        Wih1, Whh1, bih1, bhh1, lstm_out);

    const int LDS_BYTES = ATTN_LDS_FLOATS * 4;   // 78240
    hipFuncSetAttribute(reinterpret_cast<const void*>(attn_kernel),
                        hipFuncAttributeMaxDynamicSharedMemorySize, LDS_BYTES);
    attn_kernel<<<BB * (TT / TILE), 256, LDS_BYTES, stream>>>(
        lstm_out, Wq, bq, Wk, bk, Wv, bv, Wc, bc, Wo1, bo1, Wo2, bo2, out);
}

// Round 5
// 2251.648 us; speedup vs baseline: 2.3008x; 1.4722x over previous
//
#include <hip/hip_runtime.h>
#include <hip/hip_bf16.h>
#include <math.h>

#define BB   128
#define TT   2048
#define DD   4
#define HH   64
#define WIN  10
#define TILE 64
#define RWS  (TILE + WIN)   // 74 rows per attention tile (halo included)

// ---------- fast activations ----------
__device__ __forceinline__ float sigf(float x) {
    return __fdividef(1.f, 1.f + __expf(-x));
}
__device__ __forceinline__ float dot4(float4 a, float4 b) {
    return a.x*b.x + a.y*b.y + a.z*b.z + a.w*b.w;
}

// DPP quad-perm helpers (VALU-speed cross-lane within quads)
#define QB(x, imm) __int_as_float(__builtin_amdgcn_mov_dpp(__float_as_int(x), (imm), 0xF, 0xF, true))
__device__ __forceinline__ float qadd_xor1(float x) { return x + QB(x, 0xB1); }
__device__ __forceinline__ float qadd_xor2(float x) { return x + QB(x, 0x4E); }
__device__ __forceinline__ float red8(float x) {   // sum over 8-lane group
    x = qadd_xor1(x);
    x = qadd_xor2(x);
    x += __shfl_xor(x, 4, 64);
    return x;
}

// Quad-split LSTM activation: lane q=tid&3 computes gate q's activation
// (tanh via 2*sig(2z)-1, uniform code, no divergence), quad-broadcasts,
// updates c and h identically in all lanes.
__device__ __forceinline__ void act_update(const float gv0, const float gv1,
                                           const float gv2, const float gv3,
                                           const int q, float& c, float& h) {
    float y = gv0;
    y = (q == 1) ? gv1 : y;
    y = (q == 2) ? gv2 : y;
    y = (q == 3) ? gv3 : y;
    y = (q == 2) ? y + y : y;            // tanh gate: pre-scale 2x
    float s = sigf(y);
    s = (q == 2) ? s + s - 1.f : s;      // tanh(z) = 2*sig(2z)-1
    const float ii = QB(s, 0x00);
    const float ff = QB(s, 0x55);
    const float gg = QB(s, 0xAA);
    const float oo = QB(s, 0xFF);
    c = ff * c + ii * gg;
    h = oo * (2.f * sigf(c + c) - 1.f);  // oo * tanh(c)
}

// =====================================================================
// Kernel 1: 2-layer LSTM. One WG (512 threads = 8 waves) per batch.
// thread = (unit u = tid>>3, k-slice p = tid&7, 8-wide slices).
// Weights (96 floats/thread) are loaded once and PINNED via empty asm
// (R2/R3 showed the compiler rematerializes pure global loads inside the
// 2048-step loop instead of keeping ~100 VGPRs live: VGPR_Count was 76).
// Activations quad-split (8 transcendentals/step instead of ~20).
// h1 output buffered in LDS, flushed every 64 steps.
// =====================================================================
__global__ __launch_bounds__(512, 2)
void lstm_kernel(const float* __restrict__ x,
                 const float* __restrict__ Wih0, const float* __restrict__ Whh0,
                 const float* __restrict__ bih0, const float* __restrict__ bhh0,
                 const float* __restrict__ Wih1, const float* __restrict__ Whh1,
                 const float* __restrict__ bih1, const float* __restrict__ bhh1,
                 float* __restrict__ lstm_out) {
    __shared__ __align__(16) float h0s[2][HH];
    __shared__ __align__(16) float h1s[2][HH];
    __shared__ __align__(16) float xall[TT * DD];    // 32 KB
    __shared__ __align__(16) float hbuf[64 * HH];    // 16 KB output chunk

    const int tid = threadIdx.x;
    const int u   = tid >> 3;     // hidden unit 0..63
    const int p   = tid & 7;      // k-slice 0..7 (k = 8p..8p+7)
    const int q   = tid & 3;      // quad lane (gate index for activation)
    const int b   = blockIdx.x;

    // ---- weights into registers: wh0 @ wts[0..31], wi1 @ [32..63], wh1 @ [64..95]
    float wts[96];
    float wx[4], b0g[4], b1g[4];
#pragma unroll
    for (int g = 0; g < 4; ++g) {
        const int row = g * 64 + u;
        const float4 A0 = *(const float4*)(Whh0 + row * 64 + 8 * p);
        const float4 A1 = *(const float4*)(Whh0 + row * 64 + 8 * p + 4);
        const float4 B0 = *(const float4*)(Wih1 + row * 64 + 8 * p);
        const float4 B1 = *(const float4*)(Wih1 + row * 64 + 8 * p + 4);
        const float4 C0 = *(const float4*)(Whh1 + row * 64 + 8 * p);
        const float4 C1 = *(const float4*)(Whh1 + row * 64 + 8 * p + 4);
        wts[g*8+0] = A0.x; wts[g*8+1] = A0.y; wts[g*8+2] = A0.z; wts[g*8+3] = A0.w;
        wts[g*8+4] = A1.x; wts[g*8+5] = A1.y; wts[g*8+6] = A1.z; wts[g*8+7] = A1.w;
        wts[32+g*8+0] = B0.x; wts[32+g*8+1] = B0.y; wts[32+g*8+2] = B0.z; wts[32+g*8+3] = B0.w;
        wts[32+g*8+4] = B1.x; wts[32+g*8+5] = B1.y; wts[32+g*8+6] = B1.z; wts[32+g*8+7] = B1.w;
        wts[64+g*8+0] = C0.x; wts[64+g*8+1] = C0.y; wts[64+g*8+2] = C0.z; wts[64+g*8+3] = C0.w;
        wts[64+g*8+4] = C1.x; wts[64+g*8+5] = C1.y; wts[64+g*8+6] = C1.z; wts[64+g*8+7] = C1.w;
        wx[g] = (p < 4) ? Wih0[row * 4 + p] : 0.f;
        b0g[g] = bih0[row] + bhh0[row];
        b1g[g] = bih1[row] + bhh1[row];
    }
    // pin: make values opaque so the compiler cannot rematerialize the loads
#pragma unroll
    for (int i = 0; i < 96; ++i) asm volatile("" : "+v"(wts[i]));
#pragma unroll
    for (int g = 0; g < 4; ++g) asm volatile("" : "+v"(wx[g]), "+v"(b0g[g]), "+v"(b1g[g]));

    // ---- stage all x for this batch ----
    const float* xrow = x + (size_t)b * TT * DD;
    for (int i = tid; i < TT; i += 512)
        *(float4*)(xall + i * 4) = *(const float4*)(xrow + i * 4);
    if (tid < HH) h1s[1][tid] = 0.f;
    float c0 = 0.f, c1 = 0.f;
    __syncthreads();

    // ---- t=0 layer 0 (h0_prev = 0) ----
    {
        const float xa = xall[p & 3];
        float g0v[4];
#pragma unroll
        for (int g = 0; g < 4; ++g) g0v[g] = red8(wx[g] * xa) + b0g[g];
        float h0v;
        act_update(g0v[0], g0v[1], g0v[2], g0v[3], q, c0, h0v);
        if (p == 0) h0s[0][u] = h0v;
    }

    float* orow = lstm_out + (size_t)b * TT * HH;

    for (int t = 0; t < TT; ++t) {
        __syncthreads();                        // one barrier per step
        const float* h0c = h0s[t & 1];          // h0(t)
        const float* h1p = h1s[(t + 1) & 1];    // h1(t-1)
        const float4 h0a = *(const float4*)(h0c + 8 * p);
        const float4 h0b = *(const float4*)(h0c + 8 * p + 4);
        const float4 h1a = *(const float4*)(h1p + 8 * p);
        const float4 h1b = *(const float4*)(h1p + 8 * p + 4);
        float h0v[8], h1v[8];
        h0v[0]=h0a.x; h0v[1]=h0a.y; h0v[2]=h0a.z; h0v[3]=h0a.w;
        h0v[4]=h0b.x; h0v[5]=h0b.y; h0v[6]=h0b.z; h0v[7]=h0b.w;
        h1v[0]=h1a.x; h1v[1]=h1a.y; h1v[2]=h1a.z; h1v[3]=h1a.w;
        h1v[4]=h1b.x; h1v[5]=h1b.y; h1v[6]=h1b.z; h1v[7]=h1b.w;

        // layer-1 gate partials (two accumulators per gate for ILP)
        float g1v[4], g0v[4];
#pragma unroll
        for (int g = 0; g < 4; ++g) {
            float sA = 0.f, sB = 0.f;
#pragma unroll
            for (int j = 0; j < 4; ++j) {
                sA = fmaf(wts[32+g*8+j],   h0v[j],   sA);
                sB = fmaf(wts[32+g*8+4+j], h0v[4+j], sB);
                sA = fmaf(wts[64+g*8+j],   h1v[j],   sA);
                sB = fmaf(wts[64+g*8+4+j], h1v[4+j], sB);
            }
            g1v[g] = sA + sB;
        }
        // layer-0(t+1) partials
        const float xa = xall[(t + 1 < TT ? t + 1 : t) * 4 + (p & 3)];
#pragma unroll
        for (int g = 0; g < 4; ++g) {
            float sA = wx[g] * xa, sB = 0.f;
#pragma unroll
            for (int j = 0; j < 4; ++j) {
                sA = fmaf(wts[g*8+j],   h0v[j],   sA);
                sB = fmaf(wts[g*8+4+j], h0v[4+j], sB);
            }
            g0v[g] = sA + sB;
        }
#pragma unroll
        for (int g = 0; g < 4; ++g) g1v[g] = red8(g1v[g]) + b1g[g];
#pragma unroll
        for (int g = 0; g < 4; ++g) g0v[g] = red8(g0v[g]) + b0g[g];

        {   // layer-1 activations
            float h1vv;
            act_update(g1v[0], g1v[1], g1v[2], g1v[3], q, c1, h1vv);
            if (p == 0) h1s[t & 1][u] = h1vv;
            if (p == 1) hbuf[(t & 63) * HH + u] = h1vv;
        }
        if (t + 1 < TT) {   // layer-0 activations for t+1
            float h0vv;
            act_update(g0v[0], g0v[1], g0v[2], g0v[3], q, c0, h0vv);
            if (p == 0) h0s[(t + 1) & 1][u] = h0vv;
        }
        if ((t & 63) == 63) {                   // chunk flush (1 vmcnt drain / 64 steps)
            __syncthreads();
            float4*       dst = (float4*)(orow + (size_t)(t - 63) * HH);
            const float4* src = (const float4*)hbuf;
            dst[tid]       = src[tid];
            dst[512 + tid] = src[512 + tid];
        }
    }
}

// =====================================================================
// Kernel 2: fused q/k/v + windowed attention + MLP head. (unchanged R3)
// Weights read directly from global (L1/L2 broadcast across WGs); LDS
// holds only data tiles (78 KB) -> 2 WGs/CU.
// =====================================================================
#define ATTN_LDS_FLOATS 19560

__global__ __launch_bounds__(256, 2)
void attn_kernel(const float* __restrict__ lstm,
                 const float* __restrict__ Wq, const float* __restrict__ bq,
                 const float* __restrict__ Wk, const float* __restrict__ bk,
                 const float* __restrict__ Wv, const float* __restrict__ bv,
                 const float* __restrict__ Wc, const float* __restrict__ bc,
                 const float* __restrict__ Wo1, const float* __restrict__ bo1,
                 const float* __restrict__ Wo2, const float* __restrict__ bo2,
                 float* __restrict__ out) {
    extern __shared__ __align__(16) float lds[];
    float* bias = lds;            // [256]
    float* ho   = lds + 256;      // [74][64]
    float* kb   = lds + 4992;     // [74][36]
    float* qb   = lds + 7656;     // [64][36]
    float* vb   = lds + 9960;     // [74][64]
    float* swr  = lds + 14696;    // [64][12]
    float* ctxs = lds + 15464;    // [64][64]
    float* cmbs = lds + 4992;     // [64][64] alias (kb+qb dead after scores)
    float* o1s  = lds + 9960;     // [64][33] alias (vb dead after context)

    const int tid  = threadIdx.x;
    const int b    = blockIdx.x >> 5;
    const int tile = blockIdx.x & 31;
    const int t0   = tile * TILE;

    if (tid < 32) {
        bias[tid]       = bq[tid];
        bias[32 + tid]  = bk[tid];
        bias[192 + tid] = bo1[tid];
        bias[224 + tid] = Wo2[tid];
    }
    if (tid >= 64 && tid < 128) {
        const int j = tid - 64;
        bias[64 + j]  = bv[j];
        bias[128 + j] = bc[j];
    }
    for (int i = tid; i < RWS * 16; i += 256) {
        const int row = i >> 4, c = i & 15;
        const int t = t0 - WIN + row;
        float4 v = make_float4(0.f, 0.f, 0.f, 0.f);
        if (t >= 0) v = *(const float4*)(lstm + ((size_t)b * TT + t) * HH + 4 * c);
        *(float4*)(ho + row * 64 + 4 * c) = v;
    }
    __syncthreads();

    // ---- phase 1a: v projection ----
    {
        const int h = tid & 63, rq = tid >> 6;
        const int r0 = rq * 19;
        int ri[19];
        float acc[19];
#pragma unroll
        for (int rr = 0; rr < 19; ++rr) { ri[rr] = min(r0 + rr, RWS - 1); acc[rr] = bias[64 + h]; }
#pragma unroll
        for (int k4 = 0; k4 < 16; ++k4) {
            const float4 w = *(const float4*)(Wv + h * 64 + 4 * k4);
#pragma unroll
            for (int rr = 0; rr < 19; ++rr)
                acc[rr] += dot4(w, *(const float4*)(ho + ri[rr] * 64 + 4 * k4));
        }
#pragma unroll
        for (int rr = 0; rr < 19; ++rr) vb[ri[rr] * 64 + h] = acc[rr];
    }
    // ---- phase 1b: k projection ----
    {
        const int a = tid & 31, rq = tid >> 5;
        const int r0 = rq * 10;
        int ri[10];
        float acc[10];
#pragma unroll
        for (int rr = 0; rr < 10; ++rr) { ri[rr] = min(r0 + rr, RWS - 1); acc[rr] = bias[32 + a]; }
#pragma unroll
        for (int k4 = 0; k4 < 16; ++k4) {
            const float4 w = *(const float4*)(Wk + a * 64 + 4 * k4);
#pragma unroll
            for (int rr = 0; rr < 10; ++rr)
                acc[rr] += dot4(w, *(const float4*)(ho + ri[rr] * 64 + 4 * k4));
        }
#pragma unroll
        for (int rr = 0; rr < 10; ++rr) kb[ri[rr] * 36 + a] = acc[rr];
    }
    // ---- phase 1c: q projection ----
    {
        const int a = tid & 31, rq = tid >> 5;
        float acc[8];
#pragma unroll
        for (int rr = 0; rr < 8; ++rr) acc[rr] = bias[a];
#pragma unroll
        for (int k4 = 0; k4 < 16; ++k4) {
            const float4 w = *(const float4*)(Wq + a * 64 + 4 * k4);
#pragma unroll
            for (int rr = 0; rr < 8; ++rr)
                acc[rr] += dot4(w, *(const float4*)(ho + (rq * 8 + rr + WIN) * 64 + 4 * k4));
        }
#pragma unroll
        for (int rr = 0; rr < 8; ++rr) qb[(rq * 8 + rr) * 36 + a] = acc[rr];
    }
    __syncthreads();

    // ---- phase 2a: scores ----
    for (int i = tid; i < TILE * WIN; i += 256) {
        const int r = i / WIN, l = i - r * WIN;
        const int t = t0 + r;
        float s = -1e30f;
        if (t - 1 - l >= 0) {
            const int kr = r + WIN - 1 - l;
            float acc = 0.f;
#pragma unroll
            for (int a4 = 0; a4 < 8; ++a4)
                acc += dot4(*(const float4*)(qb + r * 36 + 4 * a4),
                            *(const float4*)(kb + kr * 36 + 4 * a4));
            s = acc * 0.17677669529663687f;   // 1/sqrt(32)
        }
        swr[r * 12 + l] = s;
    }
    __syncthreads();
    // ---- phase 2b: softmax per row ----
    if (tid < TILE) {
        const int r = tid;
        float sc[WIN], m = -1e30f;
#pragma unroll
        for (int l = 0; l < WIN; ++l) { sc[l] = swr[r * 12 + l]; m = fmaxf(m, sc[l]); }
        float sum = 0.f;
#pragma unroll
        for (int l = 0; l < WIN; ++l) { sc[l] = __expf(sc[l] - m); sum += sc[l]; }
        const float inv = __fdividef(1.f, sum);
#pragma unroll
        for (int l = 0; l < WIN; ++l) swr[r * 12 + l] = sc[l] * inv;
    }
    __syncthreads();
    // ---- phase 2c: context ----
    for (int i = tid; i < TILE * HH; i += 256) {
        const int r = i >> 6, h = i & 63;
        float acc = 0.f;
#pragma unroll
        for (int l = 0; l < WIN; ++l)
            acc += swr[r * 12 + l] * vb[(r + WIN - 1 - l) * 64 + h];
        ctxs[r * 64 + h] = acc;
    }
    __syncthreads();

    // ---- phase 3: combined ----
    {
        const int h = tid & 63, rq = tid >> 6;
        float acc[16];
#pragma unroll
        for (int rr = 0; rr < 16; ++rr) acc[rr] = bias[128 + h];
#pragma unroll
        for (int k4 = 0; k4 < 16; ++k4) {
            const float4 w = *(const float4*)(Wc + h * 128 + 4 * k4);
#pragma unroll
            for (int rr = 0; rr < 16; ++rr)
                acc[rr] += dot4(w, *(const float4*)(ho + (rq * 16 + rr + WIN) * 64 + 4 * k4));
        }
#pragma unroll
        for (int k4 = 0; k4 < 16; ++k4) {
            const float4 w = *(const float4*)(Wc + h * 128 + 64 + 4 * k4);
#pragma unroll
            for (int rr = 0; rr < 16; ++rr)
                acc[rr] += dot4(w, *(const float4*)(ctxs + (rq * 16 + rr) * 64 + 4 * k4));
        }
        if (t0 == 0 && rq == 0) acc[0] = ho[WIN * 64 + h];   // t==0 bypass
#pragma unroll
        for (int rr = 0; rr < 16; ++rr) cmbs[(rq * 16 + rr) * 64 + h] = acc[rr];
    }
    __syncthreads();

    // ---- phase 4: o1 ----
    {
        const int m = tid & 31, rq = tid >> 5;
        float acc[8];
#pragma unroll
        for (int rr = 0; rr < 8; ++rr) acc[rr] = bias[192 + m];
#pragma unroll
        for (int k4 = 0; k4 < 16; ++k4) {
            const float4 w = *(const float4*)(Wo1 + m * 64 + 4 * k4);
#pragma unroll
            for (int rr = 0; rr < 8; ++rr)
                acc[rr] += dot4(w, *(const float4*)(cmbs + (rq * 8 + rr) * 64 + 4 * k4));
        }
#pragma unroll
        for (int rr = 0; rr < 8; ++rr)
            o1s[(rq * 8 + rr) * 33 + m] = fmaxf(acc[rr], 0.f);
    }
    __syncthreads();

    // ---- phase 5: out ----
    if (tid < TILE) {
        const int r = tid;
        float s = bo2[0];
#pragma unroll
        for (int m = 0; m < 32; ++m) s += o1s[r * 33 + m] * bias[224 + m];
        out[(size_t)b * TT + t0 + r] = 1.5f * tanhf(s);
    }
}

// =====================================================================
extern "C" void kernel_launch(void* const* d_in, const int* in_sizes, int n_in,
                              void* d_out, int out_size, void* d_ws, size_t ws_size,
                              hipStream_t stream) {
    const float* x    = (const float*)d_in[0];
    const float* Wih0 = (const float*)d_in[1];
    const float* Whh0 = (const float*)d_in[2];
    const float* bih0 = (const float*)d_in[3];
    const float* bhh0 = (const float*)d_in[4];
    const float* Wih1 = (const float*)d_in[5];
    const float* Whh1 = (const float*)d_in[6];
    const float* bih1 = (const float*)d_in[7];
    const float* bhh1 = (const float*)d_in[8];
    const float* Wq   = (const float*)d_in[9];
    const float* bq   = (const float*)d_in[10];
    const float* Wk   = (const float*)d_in[11];
    const float* bk   = (const float*)d_in[12];
    const float* Wv   = (const float*)d_in[13];
    const float* bv   = (const float*)d_in[14];
    const float* Wc   = (const float*)d_in[15];
    const float* bc   = (const float*)d_in[16];
    const float* Wo1  = (const float*)d_in[17];
    const float* bo1  = (const float*)d_in[18];
    const float* Wo2  = (const float*)d_in[19];
    const float* bo2  = (const float*)d_in[20];
    float* out = (float*)d_out;

    float* lstm_out = (float*)d_ws;   // B*T*H floats = 64 MB

    lstm_kernel<<<BB, 512, 0, stream>>>(x, Wih0, Whh0, bih0, bhh0,
                                        Wih1, Whh1, bih1, bhh1, lstm_out);

    const int LDS_BYTES = ATTN_LDS_FLOATS * 4;   // 78240
    hipFuncSetAttribute(reinterpret_cast<const void*>(attn_kernel),
                        hipFuncAttributeMaxDynamicSharedMemorySize, LDS_BYTES);
    attn_kernel<<<BB * (TT / TILE), 256, LDS_BYTES, stream>>>(
        lstm_out, Wq, bq, Wk, bk, Wv, bv, Wc, bc, Wo1, bo1, Wo2, bo2, out);
}

// Round 8
// 2205.112 us; speedup vs baseline: 2.3493x; 1.0211x over previous
//
#include <hip/hip_runtime.h>
#include <hip/hip_bf16.h>
#include <math.h>

#define BB   128
#define TT   2048
#define DD   4
#define HH   64
#define WIN  10
#define TILE 64
#define RWS  (TILE + WIN)   // 74 rows per attention tile (halo included)

// ---------- fast activations ----------
__device__ __forceinline__ float sigf(float x) {
    return __fdividef(1.f, 1.f + __expf(-x));
}
__device__ __forceinline__ float dot4(float4 a, float4 b) {
    return a.x*b.x + a.y*b.y + a.z*b.z + a.w*b.w;
}

// DPP helpers (VALU-speed cross-lane)
#define QB(x, imm) __int_as_float(__builtin_amdgcn_mov_dpp(__float_as_int(x), (imm), 0xF, 0xF, true))
__device__ __forceinline__ float red8(float x) {   // sum over 8-lane group, pure DPP (no DS ops)
    x = x + QB(x, 0xB1);    // quad_perm xor1
    x = x + QB(x, 0x4E);    // quad_perm xor2
    x = x + QB(x, 0x141);   // row_half_mirror: quad 0-3 <-> 4-7 within each 8-group
    return x;
}

// Quad-split LSTM activation: lane q=tid&3 computes gate q's activation
// (tanh via 2*sig(2z)-1, uniform code, no divergence), quad-broadcasts,
// updates c and h identically in all lanes.
__device__ __forceinline__ void act_update(const float gv0, const float gv1,
                                           const float gv2, const float gv3,
                                           const int q, float& c, float& h) {
    float y = gv0;
    y = (q == 1) ? gv1 : y;
    y = (q == 2) ? gv2 : y;
    y = (q == 3) ? gv3 : y;
    y = (q == 2) ? y + y : y;            // tanh gate: pre-scale 2x
    float s = sigf(y);
    s = (q == 2) ? s + s - 1.f : s;      // tanh(z) = 2*sig(2z)-1
    const float ii = QB(s, 0x00);
    const float ff = QB(s, 0x55);
    const float gg = QB(s, 0xAA);
    const float oo = QB(s, 0xFF);
    c = ff * c + ii * gg;
    h = oo * (2.f * sigf(c + c) - 1.f);  // oo * tanh(c)
}

#define PIN4(v) asm volatile("" : "+v"(v.x), "+v"(v.y), "+v"(v.z), "+v"(v.w))

// =====================================================================
// Kernel 1: 2-layer LSTM. One WG (512 threads = 8 waves) per batch.
// thread = (unit u = tid>>3, k-slice p = tid&7, 8-wide slices).
// launch_bounds(512, 1): R5 showed that with min-blocks=2 (VGPR cap 256)
// the allocator SPILLED the 96 pinned weight floats to scratch
// (VGPR_Count=72) and the per-step reloads saturated L2 (~25 TB/s).
// With cap 512 the allocator has no pressure heuristic pushing spill.
// Reduction is pure-DPP (no ds ops). Activations quad-split.
// h1 output buffered in LDS, flushed every 64 steps.
// =====================================================================
__global__ __launch_bounds__(512, 1)
void lstm_kernel(const float* __restrict__ x,
                 const float* __restrict__ Wih0, const float* __restrict__ Whh0,
                 const float* __restrict__ bih0, const float* __restrict__ bhh0,
                 const float* __restrict__ Wih1, const float* __restrict__ Whh1,
                 const float* __restrict__ bih1, const float* __restrict__ bhh1,
                 float* __restrict__ lstm_out) {
    __shared__ __align__(16) float h0s[2][HH];
    __shared__ __align__(16) float h1s[2][HH];
    __shared__ __align__(16) float xall[TT * DD];    // 32 KB
    __shared__ __align__(16) float hbuf[64 * HH];    // 16 KB output chunk

    const int tid = threadIdx.x;
    const int u   = tid >> 3;     // hidden unit 0..63
    const int p   = tid & 7;      // k-slice 0..7 (k = 8p..8p+7)
    const int q   = tid & 3;      // quad lane (gate index for activation)
    const int b   = blockIdx.x;

    // ---- weights into registers (24 float4 = 96 VGPR target) ----
    float4 wh0[4][2], wi1[4][2], wh1[4][2];
    float  wx[4], b0g[4], b1g[4];
#pragma unroll
    for (int g = 0; g < 4; ++g) {
        const int row = g * 64 + u;
        wh0[g][0] = *(const float4*)(Whh0 + row * 64 + 8 * p);
        wh0[g][1] = *(const float4*)(Whh0 + row * 64 + 8 * p + 4);
        wi1[g][0] = *(const float4*)(Wih1 + row * 64 + 8 * p);
        wi1[g][1] = *(const float4*)(Wih1 + row * 64 + 8 * p + 4);
        wh1[g][0] = *(const float4*)(Whh1 + row * 64 + 8 * p);
        wh1[g][1] = *(const float4*)(Whh1 + row * 64 + 8 * p + 4);
        wx[g]  = (p < 4) ? Wih0[row * 4 + p] : 0.f;
        b0g[g] = bih0[row] + bhh0[row];
        b1g[g] = bih1[row] + bhh1[row];
    }
    // pin: opaque values -> no rematerialization of the loads
#pragma unroll
    for (int g = 0; g < 4; ++g) {
#pragma unroll
        for (int c = 0; c < 2; ++c) {
            PIN4(wh0[g][c]);
            PIN4(wi1[g][c]);
            PIN4(wh1[g][c]);
        }
        asm volatile("" : "+v"(wx[g]), "+v"(b0g[g]), "+v"(b1g[g]));
    }

    // ---- stage all x for this batch ----
    const float* xrow = x + (size_t)b * TT * DD;
    for (int i = tid; i < TT; i += 512)
        *(float4*)(xall + i * 4) = *(const float4*)(xrow + i * 4);
    if (tid < HH) h1s[1][tid] = 0.f;
    float c0 = 0.f, c1 = 0.f;
    __syncthreads();

    // ---- t=0 layer 0 (h0_prev = 0) ----
    {
        const float xa = xall[p & 3];
        float g0v[4];
#pragma unroll
        for (int g = 0; g < 4; ++g) g0v[g] = red8(wx[g] * xa) + b0g[g];
        float h0v;
        act_update(g0v[0], g0v[1], g0v[2], g0v[3], q, c0, h0v);
        if (p == 0) h0s[0][u] = h0v;
    }

    float* orow = lstm_out + (size_t)b * TT * HH;

    for (int t = 0; t < TT; ++t) {
        __syncthreads();                        // one barrier per step
        const float* h0c = h0s[t & 1];          // h0(t)
        const float* h1p = h1s[(t + 1) & 1];    // h1(t-1)
        const float4 h0a = *(const float4*)(h0c + 8 * p);
        const float4 h0b = *(const float4*)(h0c + 8 * p + 4);
        const float4 h1a = *(const float4*)(h1p + 8 * p);
        const float4 h1b = *(const float4*)(h1p + 8 * p + 4);

        // layer-1 gate partials (two accumulators per gate for ILP)
        float g1v[4], g0v[4];
#pragma unroll
        for (int g = 0; g < 4; ++g) {
            const float sA = dot4(wi1[g][0], h0a) + dot4(wh1[g][0], h1a);
            const float sB = dot4(wi1[g][1], h0b) + dot4(wh1[g][1], h1b);
            g1v[g] = sA + sB;
        }
        // layer-0(t+1) partials
        const float xa = xall[(t + 1 < TT ? t + 1 : t) * 4 + (p & 3)];
#pragma unroll
        for (int g = 0; g < 4; ++g) {
            const float sA = wx[g] * xa + dot4(wh0[g][0], h0a);
            const float sB = dot4(wh0[g][1], h0b);
            g0v[g] = sA + sB;
        }
#pragma unroll
        for (int g = 0; g < 4; ++g) g1v[g] = red8(g1v[g]) + b1g[g];
#pragma unroll
        for (int g = 0; g < 4; ++g) g0v[g] = red8(g0v[g]) + b0g[g];

        {   // layer-1 activations
            float h1vv;
            act_update(g1v[0], g1v[1], g1v[2], g1v[3], q, c1, h1vv);
            if (p == 0) h1s[t & 1][u] = h1vv;
            if (p == 1) hbuf[(t & 63) * HH + u] = h1vv;
        }
        if (t + 1 < TT) {   // layer-0 activations for t+1
            float h0vv;
            act_update(g0v[0], g0v[1], g0v[2], g0v[3], q, c0, h0vv);
            if (p == 0) h0s[(t + 1) & 1][u] = h0vv;
        }
        if ((t & 63) == 63) {                   // chunk flush (1 vmcnt drain / 64 steps)
            __syncthreads();
            float4*       dst = (float4*)(orow + (size_t)(t - 63) * HH);
            const float4* src = (const float4*)hbuf;
            dst[tid]       = src[tid];
            dst[512 + tid] = src[512 + tid];
        }
    }
}

// =====================================================================
// Kernel 2: fused q/k/v + windowed attention + MLP head. (unchanged R3)
// Weights read directly from global (L1/L2 broadcast across WGs); LDS
// holds only data tiles (78 KB) -> 2 WGs/CU.
// =====================================================================
#define ATTN_LDS_FLOATS 19560

__global__ __launch_bounds__(256, 2)
void attn_kernel(const float* __restrict__ lstm,
                 const float* __restrict__ Wq, const float* __restrict__ bq,
                 const float* __restrict__ Wk, const float* __restrict__ bk,
                 const float* __restrict__ Wv, const float* __restrict__ bv,
                 const float* __restrict__ Wc, const float* __restrict__ bc,
                 const float* __restrict__ Wo1, const float* __restrict__ bo1,
                 const float* __restrict__ Wo2, const float* __restrict__ bo2,
                 float* __restrict__ out) {
    extern __shared__ __align__(16) float lds[];
    float* bias = lds;            // [256]
    float* ho   = lds + 256;      // [74][64]
    float* kb   = lds + 4992;     // [74][36]
    float* qb   = lds + 7656;     // [64][36]
    float* vb   = lds + 9960;     // [74][64]
    float* swr  = lds + 14696;    // [64][12]
    float* ctxs = lds + 15464;    // [64][64]
    float* cmbs = lds + 4992;     // [64][64] alias (kb+qb dead after scores)
    float* o1s  = lds + 9960;     // [64][33] alias (vb dead after context)

    const int tid  = threadIdx.x;
    const int b    = blockIdx.x >> 5;
    const int tile = blockIdx.x & 31;
    const int t0   = tile * TILE;

    if (tid < 32) {
        bias[tid]       = bq[tid];
        bias[32 + tid]  = bk[tid];
        bias[192 + tid] = bo1[tid];
        bias[224 + tid] = Wo2[tid];
    }
    if (tid >= 64 && tid < 128) {
        const int j = tid - 64;
        bias[64 + j]  = bv[j];
        bias[128 + j] = bc[j];
    }
    for (int i = tid; i < RWS * 16; i += 256) {
        const int row = i >> 4, c = i & 15;
        const int t = t0 - WIN + row;
        float4 v = make_float4(0.f, 0.f, 0.f, 0.f);
        if (t >= 0) v = *(const float4*)(lstm + ((size_t)b * TT + t) * HH + 4 * c);
        *(float4*)(ho + row * 64 + 4 * c) = v;
    }
    __syncthreads();

    // ---- phase 1a: v projection ----
    {
        const int h = tid & 63, rq = tid >> 6;
        const int r0 = rq * 19;
        int ri[19];
        float acc[19];
#pragma unroll
        for (int rr = 0; rr < 19; ++rr) { ri[rr] = min(r0 + rr, RWS - 1); acc[rr] = bias[64 + h]; }
#pragma unroll
        for (int k4 = 0; k4 < 16; ++k4) {
            const float4 w = *(const float4*)(Wv + h * 64 + 4 * k4);
#pragma unroll
            for (int rr = 0; rr < 19; ++rr)
                acc[rr] += dot4(w, *(const float4*)(ho + ri[rr] * 64 + 4 * k4));
        }
#pragma unroll
        for (int rr = 0; rr < 19; ++rr) vb[ri[rr] * 64 + h] = acc[rr];
    }
    // ---- phase 1b: k projection ----
    {
        const int a = tid & 31, rq = tid >> 5;
        const int r0 = rq * 10;
        int ri[10];
        float acc[10];
#pragma unroll
        for (int rr = 0; rr < 10; ++rr) { ri[rr] = min(r0 + rr, RWS - 1); acc[rr] = bias[32 + a]; }
#pragma unroll
        for (int k4 = 0; k4 < 16; ++k4) {
            const float4 w = *(const float4*)(Wk + a * 64 + 4 * k4);
#pragma unroll
            for (int rr = 0; rr < 10; ++rr)
                acc[rr] += dot4(w, *(const float4*)(ho + ri[rr] * 64 + 4 * k4));
        }
#pragma unroll
        for (int rr = 0; rr < 10; ++rr) kb[ri[rr] * 36 + a] = acc[rr];
    }
    // ---- phase 1c: q projection ----
    {
        const int a = tid & 31, rq = tid >> 5;
        float acc[8];
#pragma unroll
        for (int rr = 0; rr < 8; ++rr) acc[rr] = bias[a];
#pragma unroll
        for (int k4 = 0; k4 < 16; ++k4) {
            const float4 w = *(const float4*)(Wq + a * 64 + 4 * k4);
#pragma unroll
            for (int rr = 0; rr < 8; ++rr)
                acc[rr] += dot4(w, *(const float4*)(ho + (rq * 8 + rr + WIN) * 64 + 4 * k4));
        }
#pragma unroll
        for (int rr = 0; rr < 8; ++rr) qb[(rq * 8 + rr) * 36 + a] = acc[rr];
    }
    __syncthreads();

    // ---- phase 2a: scores ----
    for (int i = tid; i < TILE * WIN; i += 256) {
        const int r = i / WIN, l = i - r * WIN;
        const int t = t0 + r;
        float s = -1e30f;
        if (t - 1 - l >= 0) {
            const int kr = r + WIN - 1 - l;
            float acc = 0.f;
#pragma unroll
            for (int a4 = 0; a4 < 8; ++a4)
                acc += dot4(*(const float4*)(qb + r * 36 + 4 * a4),
                            *(const float4*)(kb + kr * 36 + 4 * a4));
            s = acc * 0.17677669529663687f;   // 1/sqrt(32)
        }
        swr[r * 12 + l] = s;
    }
    __syncthreads();
    // ---- phase 2b: softmax per row ----
    if (tid < TILE) {
        const int r = tid;
        float sc[WIN], m = -1e30f;
#pragma unroll
        for (int l = 0; l < WIN; ++l) { sc[l] = swr[r * 12 + l]; m = fmaxf(m, sc[l]); }
        float sum = 0.f;
#pragma unroll
        for (int l = 0; l < WIN; ++l) { sc[l] = __expf(sc[l] - m); sum += sc[l]; }
        const float inv = __fdividef(1.f, sum);
#pragma unroll
        for (int l = 0; l < WIN; ++l) swr[r * 12 + l] = sc[l] * inv;
    }
    __syncthreads();
    // ---- phase 2c: context ----
    for (int i = tid; i < TILE * HH; i += 256) {
        const int r = i >> 6, h = i & 63;
        float acc = 0.f;
#pragma unroll
        for (int l = 0; l < WIN; ++l)
            acc += swr[r * 12 + l] * vb[(r + WIN - 1 - l) * 64 + h];
        ctxs[r * 64 + h] = acc;
    }
    __syncthreads();

    // ---- phase 3: combined ----
    {
        const int h = tid & 63, rq = tid >> 6;
        float acc[16];
#pragma unroll
        for (int rr = 0; rr < 16; ++rr) acc[rr] = bias[128 + h];
#pragma unroll
        for (int k4 = 0; k4 < 16; ++k4) {
            const float4 w = *(const float4*)(Wc + h * 128 + 4 * k4);
#pragma unroll
            for (int rr = 0; rr < 16; ++rr)
                acc[rr] += dot4(w, *(const float4*)(ho + (rq * 16 + rr + WIN) * 64 + 4 * k4));
        }
#pragma unroll
        for (int k4 = 0; k4 < 16; ++k4) {
            const float4 w = *(const float4*)(Wc + h * 128 + 64 + 4 * k4);
#pragma unroll
            for (int rr = 0; rr < 16; ++rr)
                acc[rr] += dot4(w, *(const float4*)(ctxs + (rq * 16 + rr) * 64 + 4 * k4));
        }
        if (t0 == 0 && rq == 0) acc[0] = ho[WIN * 64 + h];   // t==0 bypass
#pragma unroll
        for (int rr = 0; rr < 16; ++rr) cmbs[(rq * 16 + rr) * 64 + h] = acc[rr];
    }
    __syncthreads();

    // ---- phase 4: o1 ----
    {
        const int m = tid & 31, rq = tid >> 5;
        float acc[8];
#pragma unroll
        for (int rr = 0; rr < 8; ++rr) acc[rr] = bias[192 + m];
#pragma unroll
        for (int k4 = 0; k4 < 16; ++k4) {
            const float4 w = *(const float4*)(Wo1 + m * 64 + 4 * k4);
#pragma unroll
            for (int rr = 0; rr < 8; ++rr)
                acc[rr] += dot4(w, *(const float4*)(cmbs + (rq * 8 + rr) * 64 + 4 * k4));
        }
#pragma unroll
        for (int rr = 0; rr < 8; ++rr)
            o1s[(rq * 8 + rr) * 33 + m] = fmaxf(acc[rr], 0.f);
    }
    __syncthreads();

    // ---- phase 5: out ----
    if (tid < TILE) {
        const int r = tid;
        float s = bo2[0];
#pragma unroll
        for (int m = 0; m < 32; ++m) s += o1s[r * 33 + m] * bias[224 + m];
        out[(size_t)b * TT + t0 + r] = 1.5f * tanhf(s);
    }
}

// =====================================================================
extern "C" void kernel_launch(void* const* d_in, const int* in_sizes, int n_in,
                              void* d_out, int out_size, void* d_ws, size_t ws_size,
                              hipStream_t stream) {
    const float* x    = (const float*)d_in[0];
    const float* Wih0 = (const float*)d_in[1];
    const float* Whh0 = (const float*)d_in[2];
    const float* bih0 = (const float*)d_in[3];
    const float* bhh0 = (const float*)d_in[4];
    const float* Wih1 = (const float*)d_in[5];
    const float* Whh1 = (const float*)d_in[6];
    const float* bih1 = (const float*)d_in[7];
    const float* bhh1 = (const float*)d_in[8];
    const float* Wq   = (const float*)d_in[9];
    const float* bq   = (const float*)d_in[10];
    const float* Wk   = (const float*)d_in[11];
    const float* bk   = (const float*)d_in[12];
    const float* Wv   = (const float*)d_in[13];
    const float* bv   = (const float*)d_in[14];
    const float* Wc   = (const float*)d_in[15];
    const float* bc   = (const float*)d_in[16];
    const float* Wo1  = (const float*)d_in[17];
    const float* bo1  = (const float*)d_in[18];
    const float* Wo2  = (const float*)d_in[19];
    const float* bo2  = (const float*)d_in[20];
    float* out = (float*)d_out;

    float* lstm_out = (float*)d_ws;   // B*T*H floats = 64 MB

    lstm_kernel<<<BB, 512, 0, stream>>>(x, Wih0, Whh0, bih0, bhh0,
                                        Wih1, Whh1, bih1, bhh1, lstm_out);

    const int LDS_BYTES = ATTN_LDS_FLOATS * 4;   // 78240
    hipFuncSetAttribute(reinterpret_cast<const void*>(attn_kernel),
                        hipFuncAttributeMaxDynamicSharedMemorySize, LDS_BYTES);
    attn_kernel<<<BB * (TT / TILE), 256, LDS_BYTES, stream>>>(
        lstm_out, Wq, bq, Wk, bk, Wv, bv, Wc, bc, Wo1, bo1, Wo2, bo2, out);
}